// Round 10
// baseline (2558.378 us; speedup 1.0000x reference)
//
#include <hip/hip_runtime.h>

#define DEVINL __device__ __forceinline__

constexpr int PRE_NONE=0, PRE_COMBINE=1, PRE_BN_RELU=2, PRE_DIVCNT=3, PRE_ADD_RELU=4;

DEVINL void atomAddF(float* p, float v) {
  __hip_atomic_fetch_add(p, v, __ATOMIC_RELAXED, __HIP_MEMORY_SCOPE_AGENT);
}

// W LDS slot: 8-col groups spread so b128 reads are ≤2-way bank aliased (2-way = free)
DEVINL int wslotW(int c){ int g=c>>3; return g*8 + ((g>>2)<<2) + (c&7); }
// A^T LDS addr: row k holds 32 chunks of 4 rows, chunk-rotated by k>>2 to fix staging-write banks
DEVINL int aaddr4(int k, int rchunk){ return (k<<7) + (((rchunk + (k>>2)) & 31) << 2); }

// C[r][c] = act( pre(A)[r][:] @ W[:,c] + bias[c] ), 128 output cols, K in {16,32,128}
// PRE_BN_RELU: p0=raw col stats (sum[128],sumsq[128]), p1=gamma, p2=beta, rn=1/nrows
//              -> scale/shift computed inline (bn_fin kernel eliminated)
// STATS: accumulate column sum/sumsq of raw output into gstats[256] (shuffle-reduced)
// AUX:   write the pre-op-transformed A back to aux (may alias A; owning-thread RMW)
// NOTE: __launch_bounds__(256,2) — needs ~80-100 VGPRs; (256,4) caps at 64 -> spills (R8).
template<int K, int PRE, int STATS, int AUX, int RELU>
__global__ __launch_bounds__(256, 2)
void gemm_k(const float* A, const float* __restrict__ W,
            const float* __restrict__ bias, float* out, int nrows,
            const float* __restrict__ p0, const float* __restrict__ p1,
            const float* __restrict__ p2, float rn,
            const int* __restrict__ cnt, float* aux, float* gstats)
{
  constexpr int KC = (K < 32) ? K : 32;
  __shared__ float sA[KC*128];
  __shared__ float sW[KC*140];
  const int t = threadIdx.x;
  const int row0 = blockIdx.x << 7;
  const int rows = min(128, nrows - row0);
  const int cgrp = t & 15;
  const int rgrp = t >> 4;
  const int c0 = cgrp << 3;
  const int r0 = rgrp << 3;
  const int wb = (cgrp<<3) + ((cgrp>>2)<<2);

  float acc[8][8];
  {
    float4 b0 = *(const float4*)(bias + c0);
    float4 b1 = *(const float4*)(bias + c0 + 4);
    #pragma unroll
    for (int r=0;r<8;++r){
      acc[r][0]=b0.x; acc[r][1]=b0.y; acc[r][2]=b0.z; acc[r][3]=b0.w;
      acc[r][4]=b1.x; acc[r][5]=b1.y; acc[r][6]=b1.z; acc[r][7]=b1.w;
    }
  }
  float alpha = 1.f;
  if (PRE==PRE_COMBINE) alpha = 1.f + p0[0];

  for (int kk = 0; kk < K; kk += KC) {
    __syncthreads();
    #pragma unroll
    for (int idx = t; idx < KC*32; idx += 256) {
      int k = idx >> 5;
      int c = (idx & 31) << 2;
      float4 w = *(const float4*)(W + (size_t)(kk+k)*128 + c);
      *(float4*)(sW + k*140 + wslotW(c)) = w;
    }
    #pragma unroll
    for (int idx = t; idx < KC*32; idx += 256) {
      int r  = idx / (KC/4);
      int k4 = (idx % (KC/4)) << 2;
      float4 a = make_float4(0.f,0.f,0.f,0.f);
      if (r < rows) {
        size_t base = (size_t)(row0 + r)*K + kk + k4;
        a = *(const float4*)(A + base);
        if (PRE==PRE_COMBINE) {
          float4 b = *(const float4*)(p1 + base);
          a.x = fmaf(alpha,a.x,b.x); a.y = fmaf(alpha,a.y,b.y);
          a.z = fmaf(alpha,a.z,b.z); a.w = fmaf(alpha,a.w,b.w);
        } else if (PRE==PRE_BN_RELU) {
          int kg = kk + k4;
          float4 sm = *(const float4*)(p0 + kg);
          float4 sq = *(const float4*)(p0 + 128 + kg);
          float4 gv = *(const float4*)(p1 + kg);
          float4 bv = *(const float4*)(p2 + kg);
          float m0=sm.x*rn, m1=sm.y*rn, m2=sm.z*rn, m3=sm.w*rn;
          float sc0 = gv.x*rsqrtf(fmaf(sq.x,rn,-m0*m0)+1e-5f);
          float sc1 = gv.y*rsqrtf(fmaf(sq.y,rn,-m1*m1)+1e-5f);
          float sc2 = gv.z*rsqrtf(fmaf(sq.z,rn,-m2*m2)+1e-5f);
          float sc3 = gv.w*rsqrtf(fmaf(sq.w,rn,-m3*m3)+1e-5f);
          float sh0 = fmaf(-m0, sc0, bv.x);
          float sh1 = fmaf(-m1, sc1, bv.y);
          float sh2 = fmaf(-m2, sc2, bv.z);
          float sh3 = fmaf(-m3, sc3, bv.w);
          a.x = fmaxf(fmaf(a.x,sc0,sh0),0.f);
          a.y = fmaxf(fmaf(a.y,sc1,sh1),0.f);
          a.z = fmaxf(fmaf(a.z,sc2,sh2),0.f);
          a.w = fmaxf(fmaf(a.w,sc3,sh3),0.f);
        } else if (PRE==PRE_DIVCNT) {
          float rc = 1.f / (float)max(cnt[row0+r], 1);
          a.x*=rc; a.y*=rc; a.z*=rc; a.w*=rc;
        } else if (PRE==PRE_ADD_RELU) {
          float4 b = *(const float4*)(p1 + base);
          a.x = fmaxf(a.x+b.x,0.f); a.y = fmaxf(a.y+b.y,0.f);
          a.z = fmaxf(a.z+b.z,0.f); a.w = fmaxf(a.w+b.w,0.f);
        }
        if (AUX) *(float4*)(aux + base) = a;
      }
      int wbase = aaddr4(k4, r>>2) + (r&3);
      sA[wbase] = a.x; sA[wbase+128] = a.y; sA[wbase+256] = a.z; sA[wbase+384] = a.w;
    }
    __syncthreads();
    #pragma unroll 8
    for (int k = 0; k < KC; ++k) {
      float4 a0 = *(const float4*)(sA + aaddr4(k, rgrp<<1));
      float4 a1 = *(const float4*)(sA + aaddr4(k, (rgrp<<1)+1));
      float4 w0 = *(const float4*)(sW + k*140 + wb);
      float4 w1 = *(const float4*)(sW + k*140 + wb + 4);
      float ar[8] = {a0.x,a0.y,a0.z,a0.w,a1.x,a1.y,a1.z,a1.w};
      float wv[8] = {w0.x,w0.y,w0.z,w0.w,w1.x,w1.y,w1.z,w1.w};
      #pragma unroll
      for (int r=0;r<8;++r)
        #pragma unroll
        for (int c=0;c<8;++c)
          acc[r][c] = fmaf(ar[r], wv[c], acc[r][c]);
    }
  }

  #pragma unroll
  for (int r=0;r<8;++r) {
    int row = row0 + r0 + r;
    if (row < nrows) {
      float4 o0, o1v;
      o0.x = RELU ? fmaxf(acc[r][0],0.f) : acc[r][0];
      o0.y = RELU ? fmaxf(acc[r][1],0.f) : acc[r][1];
      o0.z = RELU ? fmaxf(acc[r][2],0.f) : acc[r][2];
      o0.w = RELU ? fmaxf(acc[r][3],0.f) : acc[r][3];
      o1v.x = RELU ? fmaxf(acc[r][4],0.f) : acc[r][4];
      o1v.y = RELU ? fmaxf(acc[r][5],0.f) : acc[r][5];
      o1v.z = RELU ? fmaxf(acc[r][6],0.f) : acc[r][6];
      o1v.w = RELU ? fmaxf(acc[r][7],0.f) : acc[r][7];
      *(float4*)(out + (size_t)row*128 + c0)     = o0;
      *(float4*)(out + (size_t)row*128 + c0 + 4) = o1v;
    }
  }

  if (STATS) {
    float s[8], q[8];
    #pragma unroll
    for (int c=0;c<8;++c){ s[c]=0.f; q[c]=0.f; }
    #pragma unroll
    for (int r=0;r<8;++r) {
      if (row0 + r0 + r < nrows) {
        #pragma unroll
        for (int c=0;c<8;++c){ float v = acc[r][c]; s[c]+=v; q[c]+=v*v; }
      }
    }
    // lanes t, t^16, t^32, t^48 share the same column group -> butterfly over bits 4,5
    #pragma unroll
    for (int c=0;c<8;++c){
      s[c] += __shfl_xor(s[c], 16); s[c] += __shfl_xor(s[c], 32);
      q[c] += __shfl_xor(q[c], 16); q[c] += __shfl_xor(q[c], 32);
    }
    __syncthreads();  // all waves done with sA -> reuse as stats staging
    int wave = t >> 6, lane = t & 63;
    if (lane < 16) {
      #pragma unroll
      for (int c=0;c<8;++c){
        sA[wave*128 + lane*8 + c]       = s[c];
        sA[512 + wave*128 + lane*8 + c] = q[c];
      }
    }
    __syncthreads();
    int col = t & 127, sel = t >> 7;
    float v = sA[sel*512 + col] + sA[sel*512 + 128 + col]
            + sA[sel*512 + 256 + col] + sA[sel*512 + 384 + col];
    atomAddF(&gstats[sel*128 + col], v);
  }
}

// ---------------- CSR build: histogram -> 2-level exclusive scan -> slot fill ----

__global__ void hist5(const int* __restrict__ dst, const int* __restrict__ fcol,
                      const int* __restrict__ frow, const int* __restrict__ batch,
                      const int* __restrict__ fbatch,
                      int E, int Fe, int N, int Fn,
                      int* cntd, int* cntf, int* cnta, int* cntb, int* cntfb)
{
  int i = blockIdx.x*256 + threadIdx.x;
  if (i < E)  atomicAdd(&cntd[dst[i]], 1);
  if (i < Fe) {
    atomicAdd(&cntf[fcol[i]], 1);
    atomicAdd(&cnta[frow[i]], 1);
  }
  if (i < N)  atomicAdd(&cntb[batch[i]], 1);
  if (i < Fn) atomicAdd(&cntfb[fbatch[i]], 1);
}

__global__ __launch_bounds__(256)
void scan_p1(const int* __restrict__ cnt, int n, int* excl, int* btot)
{
  __shared__ int sp[256];
  int t = threadIdx.x;
  int base = blockIdx.x*1024 + t*4;
  int v0=0,v1=0,v2=0,v3=0;
  if (base+0 < n) v0 = cnt[base+0];
  if (base+1 < n) v1 = cnt[base+1];
  if (base+2 < n) v2 = cnt[base+2];
  if (base+3 < n) v3 = cnt[base+3];
  int s = v0+v1+v2+v3;
  sp[t] = s; __syncthreads();
  for (int off=1; off<256; off<<=1) {
    int x = (t>=off) ? sp[t-off] : 0;
    __syncthreads();
    sp[t] += x;
    __syncthreads();
  }
  int run = sp[t] - s;  // exclusive prefix within chunk
  if (base+0 < n) { excl[base+0] = run; run += v0; }
  if (base+1 < n) { excl[base+1] = run; run += v1; }
  if (base+2 < n) { excl[base+2] = run; run += v2; }
  if (base+3 < n) { excl[base+3] = run; run += v3; }
  if (t == 0) btot[blockIdx.x] = sp[255];
}

__global__ __launch_bounds__(256)
void scan_p2(int* btot, int nb)
{
  __shared__ int sp[256];
  __shared__ int carry;
  int t = threadIdx.x;
  if (t == 0) carry = 0;
  __syncthreads();
  for (int base = 0; base < nb; base += 256) {
    int i = base + t;
    int v = (i < nb) ? btot[i] : 0;
    sp[t] = v; __syncthreads();
    for (int off=1; off<256; off<<=1) {
      int x = (t>=off) ? sp[t-off] : 0;
      __syncthreads();
      sp[t] += x;
      __syncthreads();
    }
    if (i < nb) btot[i] = sp[t] - v + carry;
    __syncthreads();
    if (t == 0) carry += sp[255];
    __syncthreads();
  }
}

__global__ void scan_p3(int* excl, int n, const int* __restrict__ btot)
{
  int i = blockIdx.x*256 + threadIdx.x;
  if (i < n) excl[i] += btot[i>>10];
}

__global__ void csr_fill(const int* __restrict__ key, int n, int* off, int* perm)
{
  int i = blockIdx.x*256 + threadIdx.x;
  if (i < n) {
    int p = atomicAdd(&off[key[i]], 1);
    perm[p] = i;
  }
}

// fuse the index chains once per call: gidx = key[perm[j]], plus permuted edge-attr rows
__global__ void prepermute(const int* __restrict__ src, const int* __restrict__ permE,
                           const float* __restrict__ ea,
                           const int* __restrict__ frow, const int* __restrict__ perm1,
                           const int* __restrict__ fcol, const int* __restrict__ perm2,
                           int E, int Fe,
                           int* esrc, float* ea_p, int* gidx1, int* gidx2)
{
  int i = blockIdx.x*256 + threadIdx.x;
  if (i < E) {
    int e = permE[i];
    esrc[i] = src[e];
    float4 a = *(const float4*)(ea + (size_t)e*8);
    float4 b = *(const float4*)(ea + (size_t)e*8 + 4);
    *(float4*)(ea_p + (size_t)i*8)     = a;
    *(float4*)(ea_p + (size_t)i*8 + 4) = b;
  }
  if (i < Fe) {
    gidx1[i] = frow[perm1[i]];
    gidx2[i] = fcol[perm2[i]];
  }
}

// ---------------- CSR consumers (gather-reduce, no feature atomics) ------------
// One node per 256-thread block; the two 128-thread halves take alternating edges
// (halves the serial dependent-load chain), partials combined via LDS.

__global__ __launch_bounds__(256)
void edge_agg_csr(const float* __restrict__ h, const float* __restrict__ ea_p,
                  const float* __restrict__ bW, const float* __restrict__ bb,
                  const int* __restrict__ esrc,
                  const int* __restrict__ offEnd, const int* __restrict__ cnt,
                  float* agg, int N)
{
  __shared__ float part[256];
  int n = blockIdx.x;
  int c = threadIdx.x & 127;
  int p = threadIdx.x >> 7;
  int end = offEnd[n], start = end - cnt[n];
  float w0=bW[0*128+c], w1=bW[1*128+c], w2=bW[2*128+c], w3=bW[3*128+c];
  float w4=bW[4*128+c], w5=bW[5*128+c], w6=bW[6*128+c], w7=bW[7*128+c];
  float bbc = bb[c];
  float s = 0.f;
  for (int j = start + p; j < end; j += 2) {
    const float* er = ea_p + (size_t)j*8;
    float v = bbc;
    v = fmaf(er[0], w0, v); v = fmaf(er[1], w1, v);
    v = fmaf(er[2], w2, v); v = fmaf(er[3], w3, v);
    v = fmaf(er[4], w4, v); v = fmaf(er[5], w5, v);
    v = fmaf(er[6], w6, v); v = fmaf(er[7], w7, v);
    v += h[(size_t)esrc[j]*128 + c];
    s += fmaxf(v, 0.f);
  }
  part[threadIdx.x] = s;
  __syncthreads();
  if (threadIdx.x < 128)
    agg[(size_t)n*128 + c] = part[c] + part[128 + c];
}

// hf[f] += mean_{segment} am[gidx[j]]
__global__ __launch_bounds__(256)
void frag_update_csr(float* hf, const float* __restrict__ am,
                     const int* __restrict__ gidx,
                     const int* __restrict__ offEnd, const int* __restrict__ cnt, int Fn)
{
  __shared__ float part[256];
  int f = blockIdx.x;
  int c = threadIdx.x & 127;
  int p = threadIdx.x >> 7;
  int end = offEnd[f], k = cnt[f], start = end - k;
  float s = 0.f;
  for (int j = start + p; j < end; j += 2)
    s += am[(size_t)gidx[j]*128 + c];
  part[threadIdx.x] = s;
  __syncthreads();
  if (threadIdx.x < 128) {
    size_t o = (size_t)f*128 + c;
    hf[o] = fmaf(part[c] + part[128 + c], 1.f/(float)max(k,1), hf[o]);
  }
}

// column sum/sumsq of an [n x 128] matrix -> gstats[256]
__global__ __launch_bounds__(256)
void col_stats(const float* __restrict__ src, int n, float* gstats)
{
  __shared__ float ss[256], qq[256];
  int c = threadIdx.x & 127, half = threadIdx.x >> 7;
  float s = 0.f, q = 0.f;
  for (int row = blockIdx.x*2 + half; row < n; row += (int)gridDim.x*2) {
    float v = src[(size_t)row*128 + c];
    s += v; q += v*v;
  }
  ss[threadIdx.x] = s; qq[threadIdx.x] = q;
  __syncthreads();
  if (threadIdx.x < 128) {
    atomAddF(&gstats[c],     ss[threadIdx.x] + ss[threadIdx.x+128]);
    atomAddF(&gstats[128+c], qq[threadIdx.x] + qq[threadIdx.x+128]);
  }
}

// h[n] += mean_{segment} fm[gidx[j]]
__global__ __launch_bounds__(256)
void f2a_csr(float* h, const float* __restrict__ fm,
             const int* __restrict__ gidx,
             const int* __restrict__ offEnd, const int* __restrict__ cnt, int N)
{
  __shared__ float part[256];
  int n = blockIdx.x;
  int k = cnt[n];
  if (k == 0) return;   // block-uniform: whole block exits before barrier
  int c = threadIdx.x & 127;
  int p = threadIdx.x >> 7;
  int end = offEnd[n], start = end - k;
  float s = 0.f;
  for (int j = start + p; j < end; j += 2)
    s += fm[(size_t)gidx[j]*128 + c];
  part[threadIdx.x] = s;
  __syncthreads();
  if (threadIdx.x < 128)
    h[(size_t)n*128 + c] += (part[c] + part[128 + c])/(float)k;
}

// pooling over a SORTED segment index: run-accumulate, flush once per run
__global__ __launch_bounds__(256)
void pool_add_sorted(const float* __restrict__ in, const int* __restrict__ idx,
                     float* acc, int n)
{
  int c = threadIdx.x & 127;
  int half = threadIdx.x >> 7;
  int row0 = blockIdx.x * 16;
  int rend = min(row0 + 16, n);
  float s = 0.f; int cur = -1;
  for (int r = row0 + half; r < rend; r += 2) {
    int id = idx[r];
    if (id != cur) {
      if (cur >= 0) atomAddF(&acc[(size_t)cur*128 + c], s);
      cur = id; s = 0.f;
    }
    s += in[(size_t)r*128 + c];
  }
  if (cur >= 0) atomAddF(&acc[(size_t)cur*128 + c], s);
}

// out[row] = o1[row][:] . W2 + b2   (Co = 1)
__global__ void final_dot(const float* __restrict__ o1, const float* __restrict__ W2,
                          const float* __restrict__ b2, float* out, int B)
{
  int row = blockIdx.x; int l = threadIdx.x; // 64 threads
  float v = fmaf(o1[(size_t)row*128 + l], W2[l],
                 o1[(size_t)row*128 + 64 + l] * W2[64+l]);
  #pragma unroll
  for (int off=32; off; off>>=1) v += __shfl_down(v, off);
  if (l==0) out[row] = v + b2[0];
}

extern "C" void kernel_launch(void* const* d_in, const int* in_sizes, int n_in,
                              void* d_out, int out_size, void* d_ws, size_t ws_size,
                              hipStream_t stream) {
  const float* x        = (const float*)d_in[0];
  const float* edge_att = (const float*)d_in[1];
  const float* frag_att = (const float*)d_in[2];
  const float* aW   = (const float*)d_in[3];
  const float* ab   = (const float*)d_in[4];
  const float* fW   = (const float*)d_in[5];
  const float* fb   = (const float*)d_in[6];
  const float* bondW= (const float*)d_in[7];
  const float* bondb= (const float*)d_in[8];
  const float* eps  = (const float*)d_in[9];
  const float* gW1  = (const float*)d_in[10];
  const float* gb1  = (const float*)d_in[11];
  const float* gng  = (const float*)d_in[12];
  const float* gnb  = (const float*)d_in[13];
  const float* gW2  = (const float*)d_in[14];
  const float* gb2  = (const float*)d_in[15];
  const float* ang  = (const float*)d_in[16];
  const float* anb  = (const float*)d_in[17];
  const float* fng  = (const float*)d_in[18];
  const float* fnb  = (const float*)d_in[19];
  const float* a2fW = (const float*)d_in[20];
  const float* a2fb = (const float*)d_in[21];
  const float* f2aW = (const float*)d_in[22];
  const float* f2ab = (const float*)d_in[23];
  const float* aoW1 = (const float*)d_in[24];
  const float* aob1 = (const float*)d_in[25];
  const float* aoW2 = (const float*)d_in[26];
  const float* aob2 = (const float*)d_in[27];
  const float* foW1 = (const float*)d_in[28];
  const float* fob1 = (const float*)d_in[29];
  const float* foW2 = (const float*)d_in[30];
  const float* fob2 = (const float*)d_in[31];
  const float* oW1  = (const float*)d_in[32];
  const float* ob1  = (const float*)d_in[33];
  const float* oW2  = (const float*)d_in[34];
  const float* ob2  = (const float*)d_in[35];
  const int* ei     = (const int*)d_in[36];
  const int* frow   = (const int*)d_in[37];
  const int* fcol   = (const int*)d_in[38];
  const int* batch  = (const int*)d_in[39];
  const int* fbatch = (const int*)d_in[40];

  const int N  = in_sizes[0]/16;
  const int E  = in_sizes[1]/8;
  const int Fn = in_sizes[2]/32;
  const int Fe = in_sizes[37];
  const int B  = out_size;     // Co == 1
  const int L  = in_sizes[9];

  float* ws = (float*)d_ws;
  size_t nh = (size_t)N*128, nf = (size_t)Fn*128, nb = (size_t)B*128;
  float* f_h    = ws;
  float* f_s0   = f_h  + nh;   // agg -> h2 (gemm2 out)
  float* f_s1   = f_s0 + nh;   // z2 (gemm1 out) -> am (gemm3 out)
  float* f_hf   = f_s1 + nh;
  float* f_fmt  = f_hf + nf;
  float* f_gacc = f_fmt + nf;
  float* f_gfacc= f_gacc + nb;
  float* f_g1   = f_gfacc + nb;
  float* f_g2   = f_g1 + nb;
  float* f_gf1  = f_g2 + nb;
  float* f_gf2  = f_gf1 + nb;
  float* f_o1   = f_gf2 + nb;
  float* f_eap  = f_o1 + nb;         // E*8 permuted edge attrs
  float* f_stats= f_eap + (size_t)E*8;  // 12 slices x 256
  float* f_scale= f_stats + 12*256;  // 128 (unused; kept for layout stability)
  float* f_shift= f_scale + 128;     // 128 (unused)
  // int region (cnt block is contiguous for the single memset)
  int* i_cntd  = (int*)(f_shift + 128);   // N
  int* i_cntf  = i_cntd + N;              // Fn
  int* i_cnta  = i_cntf + Fn;             // N
  int* i_cntb  = i_cnta + N;              // B
  int* i_cntfb = i_cntb + B;              // B
  int* i_offE  = i_cntfb + B;             // N
  int* i_off1  = i_offE + N;              // Fn
  int* i_off2  = i_off1 + Fn;             // N
  int* i_btot  = i_off2 + N;              // 256 scratch (reused serially)
  int* i_permE = i_btot + 256;            // E
  int* i_perm1 = i_permE + E;             // Fe
  int* i_perm2 = i_perm1 + Fe;            // Fe
  int* i_esrc  = i_perm2 + Fe;            // E
  int* i_gidx1 = i_esrc + E;              // Fe
  int* i_gidx2 = i_gidx1 + Fe;            // Fe

  // one memset: stats + scale/shift + count arrays (also covers i_offE; harmless)
  hipMemsetAsync(f_stats, 0,
                 (size_t)(12*256 + 256)*sizeof(float)
               + (size_t)(3*N + Fn + 2*B)*sizeof(int), stream);

  // ---- CSR build (indices are call-invariant; reused by all 4 layers) ----
  {
    int mx = max(max(E, Fe), max(N, Fn));
    hist5<<<(mx+255)/256,256,0,stream>>>(ei+E, fcol, frow, batch, fbatch,
                                         E, Fe, N, Fn,
                                         i_cntd, i_cntf, i_cnta, i_cntb, i_cntfb);
    int nbN = (N+1023)/1024, nbF = (Fn+1023)/1024;
    scan_p1<<<nbN,256,0,stream>>>(i_cntd, N, i_offE, i_btot);
    scan_p2<<<1,256,0,stream>>>(i_btot, nbN);
    scan_p3<<<(N+255)/256,256,0,stream>>>(i_offE, N, i_btot);
    scan_p1<<<nbF,256,0,stream>>>(i_cntf, Fn, i_off1, i_btot);
    scan_p2<<<1,256,0,stream>>>(i_btot, nbF);
    scan_p3<<<(Fn+255)/256,256,0,stream>>>(i_off1, Fn, i_btot);
    scan_p1<<<nbN,256,0,stream>>>(i_cnta, N, i_off2, i_btot);
    scan_p2<<<1,256,0,stream>>>(i_btot, nbN);
    scan_p3<<<(N+255)/256,256,0,stream>>>(i_off2, N, i_btot);
    csr_fill<<<(E+255)/256,256,0,stream>>>(ei+E, E, i_offE, i_permE);
    csr_fill<<<(Fe+255)/256,256,0,stream>>>(fcol, Fe, i_off1, i_perm1);
    csr_fill<<<(Fe+255)/256,256,0,stream>>>(frow, Fe, i_off2, i_perm2);
    // after fill, i_off*[k] == segment END; start = end - cnt[k]
    int mEF = max(E, Fe);
    prepermute<<<(mEF+255)/256,256,0,stream>>>(ei, i_permE, edge_att,
                                               frow, i_perm1, fcol, i_perm2,
                                               E, Fe, i_esrc, f_eap, i_gidx1, i_gidx2);
  }

  const int gN = (N+127)/128, gF = (Fn+127)/128, gB = (B+127)/128;
  const float rnN = 1.f/(float)N, rnF = 1.f/(float)Fn;

  // encoders
  gemm_k<16,PRE_NONE,0,0,0><<<gN,256,0,stream>>>(x, aW, ab, f_h, N, nullptr,nullptr,nullptr,1.f, nullptr,nullptr,nullptr);
  gemm_k<32,PRE_NONE,0,0,0><<<gF,256,0,stream>>>(frag_att, fW, fb, f_hf, Fn, nullptr,nullptr,nullptr,1.f, nullptr,nullptr,nullptr);

  for (int i=0;i<L;++i) {
    const size_t wo = (size_t)i*128*128;
    float* st0 = f_stats + (size_t)(3*i+0)*256;
    float* st1 = f_stats + (size_t)(3*i+1)*256;
    float* st2 = f_stats + (size_t)(3*i+2)*256;
    // agg = sum_{in-edges} relu(h[src] + bond(ea))
    edge_agg_csr<<<N,256,0,stream>>>(f_h, f_eap, bondW + (size_t)i*8*128,
                                     bondb + i*128, i_esrc, i_offE, i_cntd,
                                     f_s0, N);
    // z2 = ((1+eps)h + agg) @ W1 + b1 ; stats(z2)
    gemm_k<128,PRE_COMBINE,1,0,0><<<gN,256,0,stream>>>(f_h, gW1 + wo, gb1 + i*128, f_s1, N, eps+i, f_s0, nullptr,1.f, nullptr, nullptr, st0);
    // h2 = relu(bn(z2)) @ W2 + b2 ; stats(h2)   [BN folded inline from st0]
    gemm_k<128,PRE_BN_RELU,1,0,0><<<gN,256,0,stream>>>(f_s1, gW2 + wo, gb2 + i*128, f_s0, N, st0, gng+i*128, gnb+i*128, rnN, nullptr, nullptr, st1);
    // h = relu(bn(h2)) (aux->f_h) ; am = relu(h @ a2fW + b) -> f_s1
    gemm_k<128,PRE_BN_RELU,0,1,1><<<gN,256,0,stream>>>(f_s0, a2fW + wo, a2fb + i*128, f_s1, N, st1, ang+i*128, anb+i*128, rnN, nullptr, f_h, nullptr);
    // hf += seg_mean(am over fcol), then streaming stats
    frag_update_csr<<<Fn,256,0,stream>>>(f_hf, f_s1, i_gidx1, i_off1, i_cntf, Fn);
    col_stats<<<256,256,0,stream>>>(f_hf, Fn, st2);
    // hf = relu(bn(hf)) (aux in-place) ; fm = relu(hf @ f2aW + b)
    gemm_k<128,PRE_BN_RELU,0,1,1><<<gF,256,0,stream>>>(f_hf, f2aW + wo, f2ab + i*128, f_fmt, Fn, st2, fng+i*128, fnb+i*128, rnF, nullptr, f_hf, nullptr);
    // h += seg_mean(fm over frow)
    f2a_csr<<<N,256,0,stream>>>(f_h, f_fmt, i_gidx2, i_off2, i_cnta, N);
  }

  // readout (batch/fragments_batch are sorted -> run-accumulating pool)
  hipMemsetAsync(f_gacc, 0, 2*nb*4, stream);
  pool_add_sorted<<<(N+15)/16,256,0,stream>>>(f_h, batch, f_gacc, N);
  pool_add_sorted<<<(Fn+15)/16,256,0,stream>>>(f_hf, fbatch, f_gfacc, Fn);
  gemm_k<128,PRE_DIVCNT,0,0,1><<<gB,256,0,stream>>>(f_gacc, aoW1, aob1, f_g1, B, nullptr,nullptr,nullptr,1.f, i_cntb, nullptr,nullptr);
  gemm_k<128,PRE_NONE,0,0,1><<<gB,256,0,stream>>>(f_g1, aoW2, aob2, f_g2, B, nullptr,nullptr,nullptr,1.f, nullptr,nullptr,nullptr);
  gemm_k<128,PRE_DIVCNT,0,0,1><<<gB,256,0,stream>>>(f_gfacc, foW1, fob1, f_gf1, B, nullptr,nullptr,nullptr,1.f, i_cntfb, nullptr,nullptr);
  gemm_k<128,PRE_NONE,0,0,1><<<gB,256,0,stream>>>(f_gf1, foW2, fob2, f_gf2, B, nullptr,nullptr,nullptr,1.f, nullptr,nullptr,nullptr);
  gemm_k<128,PRE_ADD_RELU,0,0,1><<<gB,256,0,stream>>>(f_g2, oW1, ob1, f_o1, B, nullptr, f_gf2, nullptr,1.f, nullptr,nullptr,nullptr);
  final_dot<<<B,64,0,stream>>>(f_o1, oW2, ob2, (float*)d_out, B);
}

// Round 13
// 2450.295 us; speedup vs baseline: 1.0441x; 1.0441x over previous
//
#include <hip/hip_runtime.h>

#define DEVINL __device__ __forceinline__

constexpr int PRE_NONE=0, PRE_COMBINE=1, PRE_BN_RELU=2, PRE_DIVCNT=3, PRE_ADD_RELU=4;

DEVINL void atomAddF(float* p, float v) {
  __hip_atomic_fetch_add(p, v, __ATOMIC_RELAXED, __HIP_MEMORY_SCOPE_AGENT);
}

// W LDS slot: 8-col groups spread so b128 reads are ≤2-way bank aliased (2-way = free)
DEVINL int wslotW(int c){ int g=c>>3; return g*8 + ((g>>2)<<2) + (c&7); }
// A^T LDS addr: row k holds 32 chunks of 4 rows, chunk-rotated by k>>2 to fix staging-write banks
DEVINL int aaddr4(int k, int rchunk){ return (k<<7) + (((rchunk + (k>>2)) & 31) << 2); }

// C[r][c] = act( pre(A)[r][:] @ W[:,c] + bias[c] ), 128 output cols, K in {16,32,128}
// PRE_BN_RELU: p0=raw col stats (sum[128],sumsq[128]), p1=gamma, p2=beta, rn=1/nrows
//              -> scale/shift computed inline (bn_fin kernel eliminated; validated R10)
// STATS: accumulate column sum/sumsq of raw output into gstats[256] (shuffle-reduced)
// AUX:   write the pre-op-transformed A back to aux (may alias A; owning-thread RMW)
// NOTE: __launch_bounds__(256,2) — needs ~80-100 VGPRs; (256,4) caps at 64 -> spills (R8).
template<int K, int PRE, int STATS, int AUX, int RELU>
__global__ __launch_bounds__(256, 2)
void gemm_k(const float* A, const float* __restrict__ W,
            const float* __restrict__ bias, float* out, int nrows,
            const float* __restrict__ p0, const float* __restrict__ p1,
            const float* __restrict__ p2, float rn,
            const int* __restrict__ cnt, float* aux, float* gstats)
{
  constexpr int KC = (K < 32) ? K : 32;
  __shared__ float sA[KC*128];
  __shared__ float sW[KC*140];
  const int t = threadIdx.x;
  const int row0 = blockIdx.x << 7;
  const int rows = min(128, nrows - row0);
  const int cgrp = t & 15;
  const int rgrp = t >> 4;
  const int c0 = cgrp << 3;
  const int r0 = rgrp << 3;
  const int wb = (cgrp<<3) + ((cgrp>>2)<<2);

  float acc[8][8];
  {
    float4 b0 = *(const float4*)(bias + c0);
    float4 b1 = *(const float4*)(bias + c0 + 4);
    #pragma unroll
    for (int r=0;r<8;++r){
      acc[r][0]=b0.x; acc[r][1]=b0.y; acc[r][2]=b0.z; acc[r][3]=b0.w;
      acc[r][4]=b1.x; acc[r][5]=b1.y; acc[r][6]=b1.z; acc[r][7]=b1.w;
    }
  }
  float alpha = 1.f;
  if (PRE==PRE_COMBINE) alpha = 1.f + p0[0];

  for (int kk = 0; kk < K; kk += KC) {
    __syncthreads();
    #pragma unroll
    for (int idx = t; idx < KC*32; idx += 256) {
      int k = idx >> 5;
      int c = (idx & 31) << 2;
      float4 w = *(const float4*)(W + (size_t)(kk+k)*128 + c);
      *(float4*)(sW + k*140 + wslotW(c)) = w;
    }
    #pragma unroll
    for (int idx = t; idx < KC*32; idx += 256) {
      int r  = idx / (KC/4);
      int k4 = (idx % (KC/4)) << 2;
      float4 a = make_float4(0.f,0.f,0.f,0.f);
      if (r < rows) {
        size_t base = (size_t)(row0 + r)*K + kk + k4;
        a = *(const float4*)(A + base);
        if (PRE==PRE_COMBINE) {
          float4 b = *(const float4*)(p1 + base);
          a.x = fmaf(alpha,a.x,b.x); a.y = fmaf(alpha,a.y,b.y);
          a.z = fmaf(alpha,a.z,b.z); a.w = fmaf(alpha,a.w,b.w);
        } else if (PRE==PRE_BN_RELU) {
          int kg = kk + k4;
          float4 sm = *(const float4*)(p0 + kg);
          float4 sq = *(const float4*)(p0 + 128 + kg);
          float4 gv = *(const float4*)(p1 + kg);
          float4 bv = *(const float4*)(p2 + kg);
          float m0=sm.x*rn, m1=sm.y*rn, m2=sm.z*rn, m3=sm.w*rn;
          float sc0 = gv.x*rsqrtf(fmaf(sq.x,rn,-m0*m0)+1e-5f);
          float sc1 = gv.y*rsqrtf(fmaf(sq.y,rn,-m1*m1)+1e-5f);
          float sc2 = gv.z*rsqrtf(fmaf(sq.z,rn,-m2*m2)+1e-5f);
          float sc3 = gv.w*rsqrtf(fmaf(sq.w,rn,-m3*m3)+1e-5f);
          float sh0 = fmaf(-m0, sc0, bv.x);
          float sh1 = fmaf(-m1, sc1, bv.y);
          float sh2 = fmaf(-m2, sc2, bv.z);
          float sh3 = fmaf(-m3, sc3, bv.w);
          a.x = fmaxf(fmaf(a.x,sc0,sh0),0.f);
          a.y = fmaxf(fmaf(a.y,sc1,sh1),0.f);
          a.z = fmaxf(fmaf(a.z,sc2,sh2),0.f);
          a.w = fmaxf(fmaf(a.w,sc3,sh3),0.f);
        } else if (PRE==PRE_DIVCNT) {
          float rc = 1.f / (float)max(cnt[row0+r], 1);
          a.x*=rc; a.y*=rc; a.z*=rc; a.w*=rc;
        } else if (PRE==PRE_ADD_RELU) {
          float4 b = *(const float4*)(p1 + base);
          a.x = fmaxf(a.x+b.x,0.f); a.y = fmaxf(a.y+b.y,0.f);
          a.z = fmaxf(a.z+b.z,0.f); a.w = fmaxf(a.w+b.w,0.f);
        }
        if (AUX) *(float4*)(aux + base) = a;
      }
      int wbase = aaddr4(k4, r>>2) + (r&3);
      sA[wbase] = a.x; sA[wbase+128] = a.y; sA[wbase+256] = a.z; sA[wbase+384] = a.w;
    }
    __syncthreads();
    #pragma unroll 8
    for (int k = 0; k < KC; ++k) {
      float4 a0 = *(const float4*)(sA + aaddr4(k, rgrp<<1));
      float4 a1 = *(const float4*)(sA + aaddr4(k, (rgrp<<1)+1));
      float4 w0 = *(const float4*)(sW + k*140 + wb);
      float4 w1 = *(const float4*)(sW + k*140 + wb + 4);
      float ar[8] = {a0.x,a0.y,a0.z,a0.w,a1.x,a1.y,a1.z,a1.w};
      float wv[8] = {w0.x,w0.y,w0.z,w0.w,w1.x,w1.y,w1.z,w1.w};
      #pragma unroll
      for (int r=0;r<8;++r)
        #pragma unroll
        for (int c=0;c<8;++c)
          acc[r][c] = fmaf(ar[r], wv[c], acc[r][c]);
    }
  }

  #pragma unroll
  for (int r=0;r<8;++r) {
    int row = row0 + r0 + r;
    if (row < nrows) {
      float4 o0, o1v;
      o0.x = RELU ? fmaxf(acc[r][0],0.f) : acc[r][0];
      o0.y = RELU ? fmaxf(acc[r][1],0.f) : acc[r][1];
      o0.z = RELU ? fmaxf(acc[r][2],0.f) : acc[r][2];
      o0.w = RELU ? fmaxf(acc[r][3],0.f) : acc[r][3];
      o1v.x = RELU ? fmaxf(acc[r][4],0.f) : acc[r][4];
      o1v.y = RELU ? fmaxf(acc[r][5],0.f) : acc[r][5];
      o1v.z = RELU ? fmaxf(acc[r][6],0.f) : acc[r][6];
      o1v.w = RELU ? fmaxf(acc[r][7],0.f) : acc[r][7];
      *(float4*)(out + (size_t)row*128 + c0)     = o0;
      *(float4*)(out + (size_t)row*128 + c0 + 4) = o1v;
    }
  }

  if (STATS) {
    float s[8], q[8];
    #pragma unroll
    for (int c=0;c<8;++c){ s[c]=0.f; q[c]=0.f; }
    #pragma unroll
    for (int r=0;r<8;++r) {
      if (row0 + r0 + r < nrows) {
        #pragma unroll
        for (int c=0;c<8;++c){ float v = acc[r][c]; s[c]+=v; q[c]+=v*v; }
      }
    }
    // lanes t, t^16, t^32, t^48 share the same column group -> butterfly over bits 4,5
    #pragma unroll
    for (int c=0;c<8;++c){
      s[c] += __shfl_xor(s[c], 16); s[c] += __shfl_xor(s[c], 32);
      q[c] += __shfl_xor(q[c], 16); q[c] += __shfl_xor(q[c], 32);
    }
    __syncthreads();  // all waves done with sA -> reuse as stats staging
    int wave = t >> 6, lane = t & 63;
    if (lane < 16) {
      #pragma unroll
      for (int c=0;c<8;++c){
        sA[wave*128 + lane*8 + c]       = s[c];
        sA[512 + wave*128 + lane*8 + c] = q[c];
      }
    }
    __syncthreads();
    int col = t & 127, sel = t >> 7;
    float v = sA[sel*512 + col] + sA[sel*512 + 128 + col]
            + sA[sel*512 + 256 + col] + sA[sel*512 + 384 + col];
    atomAddF(&gstats[sel*128 + col], v);
  }
}

// ---------------- CSR build: histogram -> 2-level exclusive scan -> slot fill ----

__global__ void hist5(const int* __restrict__ dst, const int* __restrict__ fcol,
                      const int* __restrict__ frow, const int* __restrict__ batch,
                      const int* __restrict__ fbatch,
                      int E, int Fe, int N, int Fn,
                      int* cntd, int* cntf, int* cnta, int* cntb, int* cntfb)
{
  int i = blockIdx.x*256 + threadIdx.x;
  if (i < E)  atomicAdd(&cntd[dst[i]], 1);
  if (i < Fe) {
    atomicAdd(&cntf[fcol[i]], 1);
    atomicAdd(&cnta[frow[i]], 1);
  }
  if (i < N)  atomicAdd(&cntb[batch[i]], 1);
  if (i < Fn) atomicAdd(&cntfb[fbatch[i]], 1);
}

__global__ __launch_bounds__(256)
void scan_p1(const int* __restrict__ cnt, int n, int* excl, int* btot)
{
  __shared__ int sp[256];
  int t = threadIdx.x;
  int base = blockIdx.x*1024 + t*4;
  int v0=0,v1=0,v2=0,v3=0;
  if (base+0 < n) v0 = cnt[base+0];
  if (base+1 < n) v1 = cnt[base+1];
  if (base+2 < n) v2 = cnt[base+2];
  if (base+3 < n) v3 = cnt[base+3];
  int s = v0+v1+v2+v3;
  sp[t] = s; __syncthreads();
  for (int off=1; off<256; off<<=1) {
    int x = (t>=off) ? sp[t-off] : 0;
    __syncthreads();
    sp[t] += x;
    __syncthreads();
  }
  int run = sp[t] - s;  // exclusive prefix within chunk
  if (base+0 < n) { excl[base+0] = run; run += v0; }
  if (base+1 < n) { excl[base+1] = run; run += v1; }
  if (base+2 < n) { excl[base+2] = run; run += v2; }
  if (base+3 < n) { excl[base+3] = run; run += v3; }
  if (t == 0) btot[blockIdx.x] = sp[255];
}

__global__ __launch_bounds__(256)
void scan_p2(int* btot, int nb)
{
  __shared__ int sp[256];
  __shared__ int carry;
  int t = threadIdx.x;
  if (t == 0) carry = 0;
  __syncthreads();
  for (int base = 0; base < nb; base += 256) {
    int i = base + t;
    int v = (i < nb) ? btot[i] : 0;
    sp[t] = v; __syncthreads();
    for (int off=1; off<256; off<<=1) {
      int x = (t>=off) ? sp[t-off] : 0;
      __syncthreads();
      sp[t] += x;
      __syncthreads();
    }
    if (i < nb) btot[i] = sp[t] - v + carry;
    __syncthreads();
    if (t == 0) carry += sp[255];
    __syncthreads();
  }
}

__global__ void scan_p3(int* excl, int n, const int* __restrict__ btot)
{
  int i = blockIdx.x*256 + threadIdx.x;
  if (i < n) excl[i] += btot[i>>10];
}

__global__ void csr_fill(const int* __restrict__ key, int n, int* off, int* perm)
{
  int i = blockIdx.x*256 + threadIdx.x;
  if (i < n) {
    int p = atomicAdd(&off[key[i]], 1);
    perm[p] = i;
  }
}

// fuse the index chains once per call: gidx = key[perm[j]], plus permuted edge-attr rows
__global__ void prepermute(const int* __restrict__ src, const int* __restrict__ permE,
                           const float* __restrict__ ea,
                           const int* __restrict__ frow, const int* __restrict__ perm1,
                           const int* __restrict__ fcol, const int* __restrict__ perm2,
                           int E, int Fe,
                           int* esrc, float* ea_p, int* gidx1, int* gidx2)
{
  int i = blockIdx.x*256 + threadIdx.x;
  if (i < E) {
    int e = permE[i];
    esrc[i] = src[e];
    float4 a = *(const float4*)(ea + (size_t)e*8);
    float4 b = *(const float4*)(ea + (size_t)e*8 + 4);
    *(float4*)(ea_p + (size_t)i*8)     = a;
    *(float4*)(ea_p + (size_t)i*8 + 4) = b;
  }
  if (i < Fe) {
    gidx1[i] = frow[perm1[i]];
    gidx2[i] = fcol[perm2[i]];
  }
}

// ---------------- CSR consumers (gather-reduce, no feature atomics) ------------
// R9-measured-best forms: 2 nodes per 256-thread block, serial edge loop per half.
// (R10's parity-split/LDS variants measured SLOWER — kernels are at the
//  random-gather throughput ceiling, not latency-bound; keep the lean form.)

__global__ __launch_bounds__(256)
void edge_agg_csr(const float* __restrict__ h, const float* __restrict__ ea_p,
                  const float* __restrict__ bW, const float* __restrict__ bb,
                  const int* __restrict__ esrc,
                  const int* __restrict__ offEnd, const int* __restrict__ cnt,
                  float* agg, int N)
{
  int n = blockIdx.x*2 + (threadIdx.x>>7);
  if (n >= N) return;
  int c = threadIdx.x & 127;
  int end = offEnd[n], start = end - cnt[n];
  float w0=bW[0*128+c], w1=bW[1*128+c], w2=bW[2*128+c], w3=bW[3*128+c];
  float w4=bW[4*128+c], w5=bW[5*128+c], w6=bW[6*128+c], w7=bW[7*128+c];
  float bbc = bb[c];
  float s = 0.f;
  for (int j = start; j < end; ++j) {
    const float* er = ea_p + (size_t)j*8;
    float v = bbc;
    v = fmaf(er[0], w0, v); v = fmaf(er[1], w1, v);
    v = fmaf(er[2], w2, v); v = fmaf(er[3], w3, v);
    v = fmaf(er[4], w4, v); v = fmaf(er[5], w5, v);
    v = fmaf(er[6], w6, v); v = fmaf(er[7], w7, v);
    v += h[(size_t)esrc[j]*128 + c];
    s += fmaxf(v, 0.f);
  }
  agg[(size_t)n*128 + c] = s;
}

// hf[f] += mean_{segment} am[gidx[j]]
__global__ __launch_bounds__(256)
void frag_update_csr(float* hf, const float* __restrict__ am,
                     const int* __restrict__ gidx,
                     const int* __restrict__ offEnd, const int* __restrict__ cnt, int Fn)
{
  int f = blockIdx.x*2 + (threadIdx.x>>7);
  if (f >= Fn) return;
  int c = threadIdx.x & 127;
  int end = offEnd[f], k = cnt[f], start = end - k;
  float s = 0.f;
  for (int j = start; j < end; ++j) s += am[(size_t)gidx[j]*128 + c];
  size_t o = (size_t)f*128 + c;
  hf[o] = fmaf(s, 1.f/(float)max(k,1), hf[o]);
}

// column sum/sumsq of an [n x 128] matrix -> gstats[256]
__global__ __launch_bounds__(256)
void col_stats(const float* __restrict__ src, int n, float* gstats)
{
  __shared__ float ss[256], qq[256];
  int c = threadIdx.x & 127, half = threadIdx.x >> 7;
  float s = 0.f, q = 0.f;
  for (int row = blockIdx.x*2 + half; row < n; row += (int)gridDim.x*2) {
    float v = src[(size_t)row*128 + c];
    s += v; q += v*v;
  }
  ss[threadIdx.x] = s; qq[threadIdx.x] = q;
  __syncthreads();
  if (threadIdx.x < 128) {
    atomAddF(&gstats[c],     ss[threadIdx.x] + ss[threadIdx.x+128]);
    atomAddF(&gstats[128+c], qq[threadIdx.x] + qq[threadIdx.x+128]);
  }
}

// h[n] += mean_{segment} fm[gidx[j]]
__global__ __launch_bounds__(256)
void f2a_csr(float* h, const float* __restrict__ fm,
             const int* __restrict__ gidx,
             const int* __restrict__ offEnd, const int* __restrict__ cnt, int N)
{
  int n = blockIdx.x*2 + (threadIdx.x>>7);
  if (n >= N) return;
  int k = cnt[n];
  if (k == 0) return;
  int c = threadIdx.x & 127;
  int end = offEnd[n], start = end - k;
  float s = 0.f;
  for (int j = start; j < end; ++j) s += fm[(size_t)gidx[j]*128 + c];
  h[(size_t)n*128 + c] += s/(float)k;
}

// pooling over a SORTED segment index: run-accumulate, flush once per run
__global__ __launch_bounds__(256)
void pool_add_sorted(const float* __restrict__ in, const int* __restrict__ idx,
                     float* acc, int n)
{
  int c = threadIdx.x & 127;
  int half = threadIdx.x >> 7;
  int row0 = blockIdx.x * 16;
  int rend = min(row0 + 16, n);
  float s = 0.f; int cur = -1;
  for (int r = row0 + half; r < rend; r += 2) {
    int id = idx[r];
    if (id != cur) {
      if (cur >= 0) atomAddF(&acc[(size_t)cur*128 + c], s);
      cur = id; s = 0.f;
    }
    s += in[(size_t)r*128 + c];
  }
  if (cur >= 0) atomAddF(&acc[(size_t)cur*128 + c], s);
}

// out[row] = o1[row][:] . W2 + b2   (Co = 1)
__global__ void final_dot(const float* __restrict__ o1, const float* __restrict__ W2,
                          const float* __restrict__ b2, float* out, int B)
{
  int row = blockIdx.x; int l = threadIdx.x; // 64 threads
  float v = fmaf(o1[(size_t)row*128 + l], W2[l],
                 o1[(size_t)row*128 + 64 + l] * W2[64+l]);
  #pragma unroll
  for (int off=32; off; off>>=1) v += __shfl_down(v, off);
  if (l==0) out[row] = v + b2[0];
}

extern "C" void kernel_launch(void* const* d_in, const int* in_sizes, int n_in,
                              void* d_out, int out_size, void* d_ws, size_t ws_size,
                              hipStream_t stream) {
  const float* x        = (const float*)d_in[0];
  const float* edge_att = (const float*)d_in[1];
  const float* frag_att = (const float*)d_in[2];
  const float* aW   = (const float*)d_in[3];
  const float* ab   = (const float*)d_in[4];
  const float* fW   = (const float*)d_in[5];
  const float* fb   = (const float*)d_in[6];
  const float* bondW= (const float*)d_in[7];
  const float* bondb= (const float*)d_in[8];
  const float* eps  = (const float*)d_in[9];
  const float* gW1  = (const float*)d_in[10];
  const float* gb1  = (const float*)d_in[11];
  const float* gng  = (const float*)d_in[12];
  const float* gnb  = (const float*)d_in[13];
  const float* gW2  = (const float*)d_in[14];
  const float* gb2  = (const float*)d_in[15];
  const float* ang  = (const float*)d_in[16];
  const float* anb  = (const float*)d_in[17];
  const float* fng  = (const float*)d_in[18];
  const float* fnb  = (const float*)d_in[19];
  const float* a2fW = (const float*)d_in[20];
  const float* a2fb = (const float*)d_in[21];
  const float* f2aW = (const float*)d_in[22];
  const float* f2ab = (const float*)d_in[23];
  const float* aoW1 = (const float*)d_in[24];
  const float* aob1 = (const float*)d_in[25];
  const float* aoW2 = (const float*)d_in[26];
  const float* aob2 = (const float*)d_in[27];
  const float* foW1 = (const float*)d_in[28];
  const float* fob1 = (const float*)d_in[29];
  const float* foW2 = (const float*)d_in[30];
  const float* fob2 = (const float*)d_in[31];
  const float* oW1  = (const float*)d_in[32];
  const float* ob1  = (const float*)d_in[33];
  const float* oW2  = (const float*)d_in[34];
  const float* ob2  = (const float*)d_in[35];
  const int* ei     = (const int*)d_in[36];
  const int* frow   = (const int*)d_in[37];
  const int* fcol   = (const int*)d_in[38];
  const int* batch  = (const int*)d_in[39];
  const int* fbatch = (const int*)d_in[40];

  const int N  = in_sizes[0]/16;
  const int E  = in_sizes[1]/8;
  const int Fn = in_sizes[2]/32;
  const int Fe = in_sizes[37];
  const int B  = out_size;     // Co == 1
  const int L  = in_sizes[9];

  float* ws = (float*)d_ws;
  size_t nh = (size_t)N*128, nf = (size_t)Fn*128, nb = (size_t)B*128;
  float* f_h    = ws;
  float* f_s0   = f_h  + nh;   // agg -> h2 (gemm2 out)
  float* f_s1   = f_s0 + nh;   // z2 (gemm1 out) -> am (gemm3 out)
  float* f_hf   = f_s1 + nh;
  float* f_fmt  = f_hf + nf;
  float* f_gacc = f_fmt + nf;
  float* f_gfacc= f_gacc + nb;
  float* f_g1   = f_gfacc + nb;
  float* f_g2   = f_g1 + nb;
  float* f_gf1  = f_g2 + nb;
  float* f_gf2  = f_gf1 + nb;
  float* f_o1   = f_gf2 + nb;
  float* f_eap  = f_o1 + nb;         // E*8 permuted edge attrs
  float* f_stats= f_eap + (size_t)E*8;  // 12 slices x 256
  float* f_scale= f_stats + 12*256;  // 128 (unused; kept for layout stability)
  float* f_shift= f_scale + 128;     // 128 (unused)
  // int region (cnt block is contiguous for the single memset)
  int* i_cntd  = (int*)(f_shift + 128);   // N
  int* i_cntf  = i_cntd + N;              // Fn
  int* i_cnta  = i_cntf + Fn;             // N
  int* i_cntb  = i_cnta + N;              // B
  int* i_cntfb = i_cntb + B;              // B
  int* i_offE  = i_cntfb + B;             // N
  int* i_off1  = i_offE + N;              // Fn
  int* i_off2  = i_off1 + Fn;             // N
  int* i_btot  = i_off2 + N;              // 256 scratch (reused serially)
  int* i_permE = i_btot + 256;            // E
  int* i_perm1 = i_permE + E;             // Fe
  int* i_perm2 = i_perm1 + Fe;            // Fe
  int* i_esrc  = i_perm2 + Fe;            // E
  int* i_gidx1 = i_esrc + E;              // Fe
  int* i_gidx2 = i_gidx1 + Fe;            // Fe

  // one memset: stats + scale/shift + count arrays (also covers i_offE; harmless)
  hipMemsetAsync(f_stats, 0,
                 (size_t)(12*256 + 256)*sizeof(float)
               + (size_t)(3*N + Fn + 2*B)*sizeof(int), stream);

  // ---- CSR build (indices are call-invariant; reused by all 4 layers) ----
  {
    int mx = max(max(E, Fe), max(N, Fn));
    hist5<<<(mx+255)/256,256,0,stream>>>(ei+E, fcol, frow, batch, fbatch,
                                         E, Fe, N, Fn,
                                         i_cntd, i_cntf, i_cnta, i_cntb, i_cntfb);
    int nbN = (N+1023)/1024, nbF = (Fn+1023)/1024;
    scan_p1<<<nbN,256,0,stream>>>(i_cntd, N, i_offE, i_btot);
    scan_p2<<<1,256,0,stream>>>(i_btot, nbN);
    scan_p3<<<(N+255)/256,256,0,stream>>>(i_offE, N, i_btot);
    scan_p1<<<nbF,256,0,stream>>>(i_cntf, Fn, i_off1, i_btot);
    scan_p2<<<1,256,0,stream>>>(i_btot, nbF);
    scan_p3<<<(Fn+255)/256,256,0,stream>>>(i_off1, Fn, i_btot);
    scan_p1<<<nbN,256,0,stream>>>(i_cnta, N, i_off2, i_btot);
    scan_p2<<<1,256,0,stream>>>(i_btot, nbN);
    scan_p3<<<(N+255)/256,256,0,stream>>>(i_off2, N, i_btot);
    csr_fill<<<(E+255)/256,256,0,stream>>>(ei+E, E, i_offE, i_permE);
    csr_fill<<<(Fe+255)/256,256,0,stream>>>(fcol, Fe, i_off1, i_perm1);
    csr_fill<<<(Fe+255)/256,256,0,stream>>>(frow, Fe, i_off2, i_perm2);
    // after fill, i_off*[k] == segment END; start = end - cnt[k]
    int mEF = max(E, Fe);
    prepermute<<<(mEF+255)/256,256,0,stream>>>(ei, i_permE, edge_att,
                                               frow, i_perm1, fcol, i_perm2,
                                               E, Fe, i_esrc, f_eap, i_gidx1, i_gidx2);
  }

  const int gN = (N+127)/128, gF = (Fn+127)/128, gB = (B+127)/128;
  const float rnN = 1.f/(float)N, rnF = 1.f/(float)Fn;

  // encoders
  gemm_k<16,PRE_NONE,0,0,0><<<gN,256,0,stream>>>(x, aW, ab, f_h, N, nullptr,nullptr,nullptr,1.f, nullptr,nullptr,nullptr);
  gemm_k<32,PRE_NONE,0,0,0><<<gF,256,0,stream>>>(frag_att, fW, fb, f_hf, Fn, nullptr,nullptr,nullptr,1.f, nullptr,nullptr,nullptr);

  for (int i=0;i<L;++i) {
    const size_t wo = (size_t)i*128*128;
    float* st0 = f_stats + (size_t)(3*i+0)*256;
    float* st1 = f_stats + (size_t)(3*i+1)*256;
    float* st2 = f_stats + (size_t)(3*i+2)*256;
    // agg = sum_{in-edges} relu(h[src] + bond(ea))
    edge_agg_csr<<<(N+1)/2,256,0,stream>>>(f_h, f_eap, bondW + (size_t)i*8*128,
                                           bondb + i*128, i_esrc, i_offE, i_cntd,
                                           f_s0, N);
    // z2 = ((1+eps)h + agg) @ W1 + b1 ; stats(z2)
    gemm_k<128,PRE_COMBINE,1,0,0><<<gN,256,0,stream>>>(f_h, gW1 + wo, gb1 + i*128, f_s1, N, eps+i, f_s0, nullptr,1.f, nullptr, nullptr, st0);
    // h2 = relu(bn(z2)) @ W2 + b2 ; stats(h2)   [BN folded inline from st0]
    gemm_k<128,PRE_BN_RELU,1,0,0><<<gN,256,0,stream>>>(f_s1, gW2 + wo, gb2 + i*128, f_s0, N, st0, gng+i*128, gnb+i*128, rnN, nullptr, nullptr, st1);
    // h = relu(bn(h2)) (aux->f_h) ; am = relu(h @ a2fW + b) -> f_s1
    gemm_k<128,PRE_BN_RELU,0,1,1><<<gN,256,0,stream>>>(f_s0, a2fW + wo, a2fb + i*128, f_s1, N, st1, ang+i*128, anb+i*128, rnN, nullptr, f_h, nullptr);
    // hf += seg_mean(am over fcol), then streaming stats
    frag_update_csr<<<(Fn+1)/2,256,0,stream>>>(f_hf, f_s1, i_gidx1, i_off1, i_cntf, Fn);
    col_stats<<<256,256,0,stream>>>(f_hf, Fn, st2);
    // hf = relu(bn(hf)) (aux in-place) ; fm = relu(hf @ f2aW + b)
    gemm_k<128,PRE_BN_RELU,0,1,1><<<gF,256,0,stream>>>(f_hf, f2aW + wo, f2ab + i*128, f_fmt, Fn, st2, fng+i*128, fnb+i*128, rnF, nullptr, f_hf, nullptr);
    // h += seg_mean(fm over frow)
    f2a_csr<<<(N+1)/2,256,0,stream>>>(f_h, f_fmt, i_gidx2, i_off2, i_cnta, N);
  }

  // readout (batch/fragments_batch are sorted -> run-accumulating pool)
  hipMemsetAsync(f_gacc, 0, 2*nb*4, stream);
  pool_add_sorted<<<(N+15)/16,256,0,stream>>>(f_h, batch, f_gacc, N);
  pool_add_sorted<<<(Fn+15)/16,256,0,stream>>>(f_hf, fbatch, f_gfacc, Fn);
  gemm_k<128,PRE_DIVCNT,0,0,1><<<gB,256,0,stream>>>(f_gacc, aoW1, aob1, f_g1, B, nullptr,nullptr,nullptr,1.f, i_cntb, nullptr,nullptr);
  gemm_k<128,PRE_NONE,0,0,1><<<gB,256,0,stream>>>(f_g1, aoW2, aob2, f_g2, B, nullptr,nullptr,nullptr,1.f, nullptr,nullptr,nullptr);
  gemm_k<128,PRE_DIVCNT,0,0,1><<<gB,256,0,stream>>>(f_gfacc, foW1, fob1, f_gf1, B, nullptr,nullptr,nullptr,1.f, i_cntfb, nullptr,nullptr);
  gemm_k<128,PRE_NONE,0,0,1><<<gB,256,0,stream>>>(f_gf1, foW2, fob2, f_gf2, B, nullptr,nullptr,nullptr,1.f, nullptr,nullptr,nullptr);
  gemm_k<128,PRE_ADD_RELU,0,0,1><<<gB,256,0,stream>>>(f_g2, oW1, ob1, f_o1, B, nullptr, f_gf2, nullptr,1.f, nullptr,nullptr,nullptr);
  final_dot<<<B,64,0,stream>>>(f_o1, oW2, ob2, (float*)d_out, B);
}